// Round 6
// baseline (392.507 us; speedup 1.0000x reference)
//
#include <hip/hip_runtime.h>
#include <math.h>

// x: [8,512,32,32] fp32 | W_qkv: [1536,512,3,3] fp32 | W_out: [512,512,1,1]
// gamma/beta: [512] | out: [8,512,32,32] fp32
// G=8 heads, D=64 head dim, N=1024 seq (h*w), B=8

#define SMOOTH 1e-4f
#define BN_EPS 1e-5f

typedef __attribute__((ext_vector_type(8))) short bf16x8;
typedef __attribute__((ext_vector_type(4))) float f32x4;
typedef __attribute__((ext_vector_type(4))) unsigned int u32x4;
typedef __attribute__((ext_vector_type(4))) unsigned short u16x4;

__device__ inline unsigned short bf16rne(float f) {
  unsigned int u = __float_as_uint(f);
  u += 0x7fff + ((u >> 16) & 1);
  return (unsigned short)(u >> 16);
}
__device__ inline float b2f(unsigned short u) {
  return __uint_as_float((unsigned int)u << 16);
}

// ---------------------------------------------------------------------------
// Repack W_qkv [co][ci][3][3] fp32 -> wqr [t][co][ci] bf16 via LDS tile.
// wqr IS the A-fragment layout: lane(q,l15) frag = 16B at
// (t*1536+co)*512 + ci0 + q*8 -> conv reads A straight from global (L1-hot).
// ---------------------------------------------------------------------------
__global__ void repack_w(const float* __restrict__ wq,
                         unsigned short* __restrict__ wqr) {
  __shared__ float Ws[2304];  // 256 pairs x 9 taps
  const int tid = threadIdx.x;
  const size_t pair0 = (size_t)blockIdx.x * 256;
  for (int off = tid; off < 576; off += 256)
    *(float4*)(Ws + off * 4) = *(const float4*)(wq + pair0 * 9 + off * 4);
  __syncthreads();
  // LDS read stride 9 (odd) -> conflict-free across lanes.
#pragma unroll
  for (int t = 0; t < 9; ++t)
    wqr[(size_t)t * 786432 + pair0 + tid] = bf16rne(Ws[tid * 9 + t]);
}

// ---------------------------------------------------------------------------
// Repack x [b][ci][p] fp32 -> xr [b][p][ci] bf16 via LDS tile transpose.
// Tile 64 ci x 128 p, both sides coalesced; each thread writes 8 u16x4 =
// a full 32-ci half-row (256 thr x 32 = 8192 = full tile).
// ---------------------------------------------------------------------------
__global__ void repack_x(const float* __restrict__ x,
                         unsigned short* __restrict__ xr) {
  __shared__ float Xs[64 * 132];  // rows padded to 132 floats
  const int tid = threadIdx.x;
  const int p0 = (blockIdx.x & 7) * 128;
  const int ci0 = ((blockIdx.x >> 3) & 7) * 64;
  const int b = blockIdx.x >> 6;
  for (int k = 0; k < 8; ++k) {
    int idx = tid + k * 256;         // 2048 float4s
    int c4 = idx & 31, row = idx >> 5;
    *(float4*)(Xs + row * 132 + c4 * 4) =
        *(const float4*)(x + ((size_t)(b * 512 + ci0 + row)) * 1024 + p0 + c4 * 4);
  }
  __syncthreads();
  const int pl = tid >> 1, half = tid & 1;
#pragma unroll
  for (int v = 0; v < 8; ++v) {
    u16x4 pk;
#pragma unroll
    for (int e = 0; e < 4; ++e)
      pk[e] = bf16rne(Xs[(half * 32 + v * 4 + e) * 132 + pl]);
    *(u16x4*)(xr + ((size_t)(b * 1024) + p0 + pl) * 512 + ci0 + half * 32 + v * 4) = pk;
  }
}

// Repack W_out fp32 -> bf16 (layout already [co][ci], coalesced both sides).
__global__ void repack_wo(const float* __restrict__ wo,
                          unsigned short* __restrict__ wor) {
  int idx = blockIdx.x * 256 + threadIdx.x;  // 262144
  wor[idx] = bf16rne(wo[idx]);
}

// ---------------------------------------------------------------------------
// Kernel 1: 3x3 conv bf16 MFMA implicit GEMM.
// Block 64co x 256n (8h x 32w), 4 waves side-by-side in n; wave 64co x 64n.
// A (weights) is NOT staged in LDS: fragments load direct from global wqr
// (wave-uniform rows -> L1 hits across waves; VMEM pipe overlaps LDS+MFMA),
// software-pipelined one tap ahead. LDS holds only the X tile (27.2 KB ->
// 3-4 blocks/CU). Per tap: 4 global A-frags + 4 ds_read_b128 B-frags ->
// 16 MFMA. LDS traffic/block-iter ~165 KB < MFMA 2794 cyc -> MFMA-bound.
// ---------------------------------------------------------------------------
__global__ __launch_bounds__(256, 3) void conv3x3_mfma(
    const unsigned short* __restrict__ wqr,
    const unsigned short* __restrict__ xr,
    unsigned short* __restrict__ qt, unsigned short* __restrict__ kt,
    unsigned short* __restrict__ vt) {
  __shared__ __align__(16) unsigned short Xl[10 * 34 * 40];  // 27200 B

  const int tid = threadIdx.x;
  const int lane = tid & 63;
  const int wave = tid >> 6;
  const int wn = wave * 64;         // wave's n offset in the 256-n block tile
  const int l15 = lane & 15;
  const int quad = lane >> 4;
  const int h0 = blockIdx.x * 8;    // 8 h-rows per block
  const int co0 = blockIdx.y * 64;
  const int b = blockIdx.z;

  f32x4 acc[4][4];  // [ma co-tile][nb n-tile]
  for (int ma = 0; ma < 4; ++ma)
    for (int nb = 0; nb < 4; ++nb) acc[ma][nb] = (f32x4){0.f, 0.f, 0.f, 0.f};

  for (int ci0 = 0; ci0 < 512; ci0 += 32) {
    // A-frag base for this ci chunk (per-lane, 16B granule).
    const unsigned short* wbase =
        wqr + (size_t)(co0 + l15) * 512 + ci0 + quad * 8;
    // Prefetch tap-0 A-frags before staging (covers global latency).
    bf16x8 afc[4];
#pragma unroll
    for (int ma = 0; ma < 4; ++ma)
      afc[ma] = *(const bf16x8*)(wbase + ma * 16 * 512);

    __syncthreads();  // prior iter's Xl readers done
    // Stage X chunk with halo: 10 hh x 34 wi x 32 ci (1360 granules)
    for (int idx = tid; idx < 1360; idx += 256) {
      int c4 = idx & 3;
      int r = idx >> 2;
      int wi = r % 34;
      int hh = r / 34;
      int h = h0 - 1 + hh;
      int w = wi - 1;
      u32x4 v = {0u, 0u, 0u, 0u};
      if ((unsigned)h < 32u && (unsigned)w < 32u)
        v = *(const u32x4*)(xr + ((size_t)((b * 32 + h) * 32 + w) * 512 + ci0 + c4 * 8));
      *(u32x4*)(Xl + (hh * 34 + wi) * 40 + c4 * 8) = v;
    }
    __syncthreads();

#pragma unroll 1
    for (int t = 0; t < 9; ++t) {
      // Prefetch next tap's A-frags (global) before this tap's MFMAs.
      bf16x8 afn[4];
      if (t < 8) {
        const unsigned short* wp = wbase + (size_t)(t + 1) * 786432;
#pragma unroll
        for (int ma = 0; ma < 4; ++ma)
          afn[ma] = *(const bf16x8*)(wp + ma * 16 * 512);
      }
      const int ky = t / 3, kx = t - ky * 3;
      bf16x8 bfr[4];
#pragma unroll
      for (int nb = 0; nb < 4; ++nb) {
        int n = wn + nb * 16 + l15;
        int hh = (n >> 5) + ky;
        int wi = (n & 31) + kx;
        bfr[nb] = *(const bf16x8*)(Xl + (hh * 34 + wi) * 40 + quad * 8);
      }
#pragma unroll
      for (int ma = 0; ma < 4; ++ma)
#pragma unroll
        for (int nb = 0; nb < 4; ++nb)
          acc[ma][nb] = __builtin_amdgcn_mfma_f32_16x16x32_bf16(
              afc[ma], bfr[nb], acc[ma][nb], 0, 0, 0);
#pragma unroll
      for (int ma = 0; ma < 4; ++ma) afc[ma] = afn[ma];
    }
  }

  // Epilogue: C/D layout col(n)=lane&15, row(m)=quad*4+reg.
  const int sec = co0 >> 9;
  const int g = (co0 & 511) >> 6;
  const int bg = b * 8 + g;
  if (sec < 2) {
    unsigned short* dst = (sec == 0) ? qt : kt;
#pragma unroll
    for (int ma = 0; ma < 4; ++ma)
#pragma unroll
      for (int nb = 0; nb < 4; ++nb) {
        int n = wn + nb * 16 + l15;
        int p = (h0 + (n >> 5)) * 32 + (n & 31);
        int db = ma * 16 + quad * 4;
        u16x4 pk;
#pragma unroll
        for (int r = 0; r < 4; ++r) pk[r] = bf16rne(acc[ma][nb][r]);
        *(u16x4*)(dst + ((size_t)bg * 1024 + p) * 64 + db) = pk;
      }
  } else {
#pragma unroll
    for (int ma = 0; ma < 4; ++ma)
#pragma unroll
      for (int nb = 0; nb < 4; ++nb) {
        int n = wn + nb * 16 + l15;
        int p = (h0 + (n >> 5)) * 32 + (n & 31);
#pragma unroll
        for (int r = 0; r < 4; ++r) {
          int d = ma * 16 + quad * 4 + r;
          vt[((size_t)bg * 64 + d) * 1024 + p] = bf16rne(acc[ma][nb][r]);
        }
      }
  }
}

// ---------------------------------------------------------------------------
// Kernel 2: row norms from bf16 qt/kt ([bg][i][64] d-contiguous).
// ---------------------------------------------------------------------------
__global__ void norms_kernel(const unsigned short* __restrict__ qt,
                             const unsigned short* __restrict__ kt,
                             float* __restrict__ qn, float* __restrict__ kn) {
  int t = blockIdx.x * 256 + threadIdx.x;  // 65536 = bg*1024 + i
  const unsigned short* qp = qt + (size_t)t * 64;
  const unsigned short* kp = kt + (size_t)t * 64;
  float sq = 0.f, sk = 0.f;
  for (int c = 0; c < 64; c += 8) {
    bf16x8 qv = *(const bf16x8*)(qp + c);
    bf16x8 kv = *(const bf16x8*)(kp + c);
#pragma unroll
    for (int e = 0; e < 8; ++e) {
      float q = b2f((unsigned short)qv[e]);
      float k = b2f((unsigned short)kv[e]);
      sq = fmaf(q, q, sq);
      sk = fmaf(k, k, sk);
    }
  }
  qn[t] = sqrtf(sq + SMOOTH);
  kn[t] = sqrtf(sk + SMOOTH);
}

// ---------------------------------------------------------------------------
// Kernel 3: attention, bf16 MFMA. Block = 128 i x (b,g); 4 waves, 32 i each.
// ---------------------------------------------------------------------------
__global__ __launch_bounds__(256) void attn_mfma(
    const unsigned short* __restrict__ qt, const unsigned short* __restrict__ kt,
    const unsigned short* __restrict__ vt, const float* __restrict__ qn,
    const float* __restrict__ kn, unsigned short* __restrict__ aob) {
  __shared__ __align__(16) unsigned short Kl[64 * 72];   // [j][d] rows 144B
  __shared__ __align__(16) unsigned short Vl[64 * 72];   // [d][j]
  __shared__ __align__(16) unsigned short Sl[128 * 72];  // [i][j] (per-wave)

  const int tid = threadIdx.x;
  const int lane = tid & 63, wave = tid >> 6;
  const int l15 = lane & 15, quad = lane >> 4;
  const int bg = blockIdx.x;
  const int i0 = blockIdx.y * 128;
  const int iw = i0 + wave * 32;
  const int b = bg >> 3, g = bg & 7;

  bf16x8 qf[2][2];
#pragma unroll
  for (int ma = 0; ma < 2; ++ma)
#pragma unroll
    for (int ks = 0; ks < 2; ++ks)
      qf[ma][ks] = *(const bf16x8*)(
          qt + ((size_t)bg * 1024 + iw + ma * 16 + l15) * 64 + ks * 32 + quad * 8);

  float qn_i[2][4];
#pragma unroll
  for (int ma = 0; ma < 2; ++ma)
#pragma unroll
    for (int r = 0; r < 4; ++r)
      qn_i[ma][r] = qn[bg * 1024 + iw + ma * 16 + quad * 4 + r];

  f32x4 oacc[2][4];
  for (int mf = 0; mf < 2; ++mf)
    for (int nf = 0; nf < 4; ++nf) oacc[mf][nf] = (f32x4){0.f, 0.f, 0.f, 0.f};

  unsigned short* Sw = Sl + wave * 32 * 72;

  for (int jt = 0; jt < 16; ++jt) {
    const int j0 = jt * 64;
    __syncthreads();
    for (int idx = tid; idx < 512; idx += 256) {
      int c8 = idx & 7, row = idx >> 3;
      *(u32x4*)(Kl + row * 72 + c8 * 8) =
          *(const u32x4*)(kt + ((size_t)bg * 1024 + j0 + row) * 64 + c8 * 8);
      *(u32x4*)(Vl + row * 72 + c8 * 8) =
          *(const u32x4*)(vt + ((size_t)bg * 64 + row) * 1024 + j0 + c8 * 8);
    }
    __syncthreads();

    f32x4 sacc[2][4];
    for (int ma = 0; ma < 2; ++ma)
      for (int nb = 0; nb < 4; ++nb) sacc[ma][nb] = (f32x4){0.f, 0.f, 0.f, 0.f};
#pragma unroll
    for (int ks = 0; ks < 2; ++ks) {
      bf16x8 kf[4];
#pragma unroll
      for (int nb = 0; nb < 4; ++nb)
        kf[nb] = *(const bf16x8*)(Kl + (l15 + 16 * nb) * 72 + ks * 32 + quad * 8);
#pragma unroll
      for (int ma = 0; ma < 2; ++ma)
#pragma unroll
        for (int nb = 0; nb < 4; ++nb)
          sacc[ma][nb] = __builtin_amdgcn_mfma_f32_16x16x32_bf16(
              qf[ma][ks], kf[nb], sacc[ma][nb], 0, 0, 0);
    }

    float kn_j[4];
#pragma unroll
    for (int nb = 0; nb < 4; ++nb) kn_j[nb] = kn[bg * 1024 + j0 + l15 + 16 * nb];
#pragma unroll
    for (int ma = 0; ma < 2; ++ma)
#pragma unroll
      for (int nb = 0; nb < 4; ++nb)
#pragma unroll
        for (int r = 0; r < 4; ++r) {
          float s = sacc[ma][nb][r] / (qn_i[ma][r] * kn_j[nb] + SMOOTH);
          Sw[(ma * 16 + quad * 4 + r) * 72 + l15 + 16 * nb] = bf16rne(s);
        }
    // Sw is wave-private: lgkmcnt orders write->read, no barrier needed.
#pragma unroll
    for (int ks2 = 0; ks2 < 2; ++ks2) {
      bf16x8 sa[2];
#pragma unroll
      for (int mf = 0; mf < 2; ++mf)
        sa[mf] = *(const bf16x8*)(Sw + (mf * 16 + l15) * 72 + ks2 * 32 + quad * 8);
#pragma unroll
      for (int nf = 0; nf < 4; ++nf) {
        bf16x8 vb = *(const bf16x8*)(Vl + (l15 + 16 * nf) * 72 + ks2 * 32 + quad * 8);
#pragma unroll
        for (int mf = 0; mf < 2; ++mf)
          oacc[mf][nf] = __builtin_amdgcn_mfma_f32_16x16x32_bf16(
              sa[mf], vb, oacc[mf][nf], 0, 0, 0);
      }
    }
  }

#pragma unroll
  for (int mf = 0; mf < 2; ++mf)
#pragma unroll
    for (int nf = 0; nf < 4; ++nf)
#pragma unroll
      for (int r = 0; r < 4; ++r) {
        int i = iw + mf * 16 + quad * 4 + r;
        int d = l15 + 16 * nf;
        aob[((size_t)(b * 1024) + i) * 512 + g * 64 + d] = bf16rne(oacc[mf][nf][r]);
      }
}

// ---------------------------------------------------------------------------
// Kernel 4a: zero BN stat accumulators.
// ---------------------------------------------------------------------------
__global__ void zero_stats(float* __restrict__ sums, float* __restrict__ sumsq) {
  int t = blockIdx.x * 256 + threadIdx.x;
  if (t < 512) {
    sums[t] = 0.f;
    sumsq[t] = 0.f;
  }
}

// ---------------------------------------------------------------------------
// Kernel 4: 1x1 conv bf16 MFMA (M=512co, N=8192p, K=512ci) + BN stats.
// ---------------------------------------------------------------------------
__global__ __launch_bounds__(256) void conv1x1_mfma(
    const unsigned short* __restrict__ wor, const unsigned short* __restrict__ aob,
    float* __restrict__ y, float* __restrict__ sums, float* __restrict__ sumsq) {
  __shared__ __align__(16) unsigned short Wl[64 * 40];   // [co][ci] rows 80B
  __shared__ __align__(16) unsigned short Bl[128 * 40];  // [p][ci]

  const int tid = threadIdx.x;
  const int lane = tid & 63, wave = tid >> 6;
  const int l15 = lane & 15, quad = lane >> 4;
  const int wco = (wave & 1) * 32;
  const int wn = (wave >> 1) * 64;
  const int p0 = blockIdx.x * 128;
  const int co0 = blockIdx.y * 64;
  const int b = blockIdx.z;

  f32x4 acc[2][4];
  for (int ma = 0; ma < 2; ++ma)
    for (int nb = 0; nb < 4; ++nb) acc[ma][nb] = (f32x4){0.f, 0.f, 0.f, 0.f};

  for (int ci0 = 0; ci0 < 512; ci0 += 32) {
    __syncthreads();
    {
      int c8 = tid & 3, co = tid >> 2;
      *(u32x4*)(Wl + co * 40 + c8 * 8) =
          *(const u32x4*)(wor + (size_t)(co0 + co) * 512 + ci0 + c8 * 8);
    }
#pragma unroll
    for (int it = 0; it < 2; ++it) {
      int idx = tid + it * 256;
      int c8 = idx & 3, p = idx >> 2;
      *(u32x4*)(Bl + p * 40 + c8 * 8) =
          *(const u32x4*)(aob + ((size_t)(b * 1024) + p0 + p) * 512 + ci0 + c8 * 8);
    }
    __syncthreads();

    bf16x8 af[2];
#pragma unroll
    for (int ma = 0; ma < 2; ++ma)
      af[ma] = *(const bf16x8*)(Wl + (wco + ma * 16 + l15) * 40 + quad * 8);
#pragma unroll
    for (int nb = 0; nb < 4; ++nb) {
      bf16x8 bfr = *(const bf16x8*)(Bl + (wn + nb * 16 + l15) * 40 + quad * 8);
#pragma unroll
      for (int ma = 0; ma < 2; ++ma)
        acc[ma][nb] = __builtin_amdgcn_mfma_f32_16x16x32_bf16(
            af[ma], bfr, acc[ma][nb], 0, 0, 0);
    }
  }

#pragma unroll
  for (int ma = 0; ma < 2; ++ma)
#pragma unroll
    for (int r = 0; r < 4; ++r) {
      int co = co0 + wco + ma * 16 + quad * 4 + r;
      float s1 = 0.f, s2 = 0.f;
#pragma unroll
      for (int nb = 0; nb < 4; ++nb) {
        float v = acc[ma][nb][r];
        y[((size_t)(b * 512) + co) * 1024 + p0 + wn + nb * 16 + l15] = v;
        s1 += v;
        s2 = fmaf(v, v, s2);
      }
      for (int off = 8; off >= 1; off >>= 1) {
        s1 += __shfl_down(s1, off, 16);
        s2 += __shfl_down(s2, off, 16);
      }
      if (l15 == 0) {
        atomicAdd(&sums[co], s1);
        atomicAdd(&sumsq[co], s2);
      }
    }
}

// ---------------------------------------------------------------------------
// Kernel 5: BatchNorm (batch stats, biased var) + ReLU, float4.
// ---------------------------------------------------------------------------
__global__ void bn_kernel(const float* __restrict__ y,
                          const float* __restrict__ sums,
                          const float* __restrict__ sumsq,
                          const float* __restrict__ gamma,
                          const float* __restrict__ beta,
                          float* __restrict__ out) {
  int idx = blockIdx.x * 256 + threadIdx.x;  // 1048576 float4s
  int c = (idx >> 8) & 511;
  float4 v = ((const float4*)y)[idx];
  float mean = sums[c] * (1.f / 8192.f);
  float var = sumsq[c] * (1.f / 8192.f) - mean * mean;
  float sc = gamma[c] * rsqrtf(var + BN_EPS);
  float sh = beta[c] - mean * sc;
  float4 r;
  r.x = fmaxf(0.f, fmaf(v.x, sc, sh));
  r.y = fmaxf(0.f, fmaf(v.y, sc, sh));
  r.z = fmaxf(0.f, fmaf(v.z, sc, sh));
  r.w = fmaxf(0.f, fmaf(v.w, sc, sh));
  ((float4*)out)[idx] = r;
}

// ---------------------------------------------------------------------------
extern "C" void kernel_launch(void* const* d_in, const int* in_sizes, int n_in,
                              void* d_out, int out_size, void* d_ws,
                              size_t ws_size, hipStream_t stream) {
  const float* x = (const float*)d_in[0];
  const float* wq = (const float*)d_in[1];
  const float* wo = (const float*)d_in[2];
  const float* gamma = (const float*)d_in[3];
  const float* beta = (const float*)d_in[4];
  float* out = (float*)d_out;

  // Workspace layout (~74 MB, all 16B aligned)
  unsigned short* qt = (unsigned short*)d_ws;          // [64][1024][64]
  unsigned short* kt = qt + (size_t)4194304;
  unsigned short* vt = kt + (size_t)4194304;           // [64][64][1024]
  unsigned short* aob = vt + (size_t)4194304;          // [8][1024][512]
  unsigned short* wqr = aob + (size_t)4194304;         // [9][1536][512]
  unsigned short* wor = wqr + (size_t)7077888;         // [512][512]
  unsigned short* xr = wor + (size_t)262144;           // [8][1024][512]
  float* qn = (float*)(xr + (size_t)4194304);          // [64][1024]
  float* kn = qn + 65536;
  float* y = kn + 65536;                               // [8][512][1024] fp32
  float* sums = y + (size_t)4194304;
  float* sumsq = sums + 512;

  repack_w<<<dim3(3072), 256, 0, stream>>>(wq, wqr);
  repack_x<<<dim3(512), 256, 0, stream>>>(x, xr);
  repack_wo<<<dim3(1024), 256, 0, stream>>>(wo, wor);
  conv3x3_mfma<<<dim3(4, 24, 8), 256, 0, stream>>>(wqr, xr, qt, kt, vt);
  norms_kernel<<<dim3(256), 256, 0, stream>>>(qt, kt, qn, kn);
  zero_stats<<<dim3(2), 256, 0, stream>>>(sums, sumsq);
  attn_mfma<<<dim3(64, 8), 256, 0, stream>>>(qt, kt, vt, qn, kn, aob);
  conv1x1_mfma<<<dim3(8, 8, 8), 256, 0, stream>>>(wor, aob, y, sums, sumsq);
  bn_kernel<<<dim3(4096), 256, 0, stream>>>(y, sums, sumsq, gamma, beta, out);
}

// Round 7
// 332.694 us; speedup vs baseline: 1.1798x; 1.1798x over previous
//
#include <hip/hip_runtime.h>
#include <math.h>

// x: [8,512,32,32] fp32 | W_qkv: [1536,512,3,3] fp32 | W_out: [512,512,1,1]
// gamma/beta: [512] | out: [8,512,32,32] fp32
// G=8 heads, D=64 head dim, N=1024 seq (h*w), B=8

#define SMOOTH 1e-4f
#define BN_EPS 1e-5f

typedef __attribute__((ext_vector_type(8))) short bf16x8;
typedef __attribute__((ext_vector_type(4))) float f32x4;
typedef __attribute__((ext_vector_type(4))) unsigned int u32x4;
typedef __attribute__((ext_vector_type(4))) unsigned short u16x4;

__device__ inline unsigned short bf16rne(float f) {
  unsigned int u = __float_as_uint(f);
  u += 0x7fff + ((u >> 16) & 1);
  return (unsigned short)(u >> 16);
}
__device__ inline float b2f(unsigned short u) {
  return __uint_as_float((unsigned int)u << 16);
}
__device__ inline float fastrcp(float x) {
#if __has_builtin(__builtin_amdgcn_rcpf)
  return __builtin_amdgcn_rcpf(x);
#else
  return 1.0f / x;
#endif
}

// ---------------------------------------------------------------------------
// Repack W_qkv [co][ci][3][3] fp32 -> wqr [t][co][ci] bf16 via LDS tile.
// ---------------------------------------------------------------------------
__global__ void repack_w(const float* __restrict__ wq,
                         unsigned short* __restrict__ wqr) {
  __shared__ float Ws[2304];  // 256 pairs x 9 taps
  const int tid = threadIdx.x;
  const size_t pair0 = (size_t)blockIdx.x * 256;
  for (int off = tid; off < 576; off += 256)
    *(float4*)(Ws + off * 4) = *(const float4*)(wq + pair0 * 9 + off * 4);
  __syncthreads();
  // LDS read stride 9 (odd) -> conflict-free across lanes.
#pragma unroll
  for (int t = 0; t < 9; ++t)
    wqr[(size_t)t * 786432 + pair0 + tid] = bf16rne(Ws[tid * 9 + t]);
}

// ---------------------------------------------------------------------------
// Repack x [b][ci][p] fp32 -> xr [b][p][ci] bf16 via LDS tile transpose.
// ---------------------------------------------------------------------------
__global__ void repack_x(const float* __restrict__ x,
                         unsigned short* __restrict__ xr) {
  __shared__ float Xs[64 * 132];  // rows padded to 132 floats
  const int tid = threadIdx.x;
  const int p0 = (blockIdx.x & 7) * 128;
  const int ci0 = ((blockIdx.x >> 3) & 7) * 64;
  const int b = blockIdx.x >> 6;
  for (int k = 0; k < 8; ++k) {
    int idx = tid + k * 256;         // 2048 float4s
    int c4 = idx & 31, row = idx >> 5;
    *(float4*)(Xs + row * 132 + c4 * 4) =
        *(const float4*)(x + ((size_t)(b * 512 + ci0 + row)) * 1024 + p0 + c4 * 4);
  }
  __syncthreads();
  const int pl = tid >> 1, half = tid & 1;
#pragma unroll
  for (int v = 0; v < 8; ++v) {
    u16x4 pk;
#pragma unroll
    for (int e = 0; e < 4; ++e)
      pk[e] = bf16rne(Xs[(half * 32 + v * 4 + e) * 132 + pl]);
    *(u16x4*)(xr + ((size_t)(b * 1024) + p0 + pl) * 512 + ci0 + half * 32 + v * 4) = pk;
  }
}

// Repack W_out fp32 -> bf16 (layout already [co][ci], coalesced both sides).
__global__ void repack_wo(const float* __restrict__ wo,
                          unsigned short* __restrict__ wor) {
  int idx = blockIdx.x * 256 + threadIdx.x;  // 262144
  wor[idx] = bf16rne(wo[idx]);
}

// ---------------------------------------------------------------------------
// Kernel 1: 3x3 conv bf16 MFMA implicit GEMM (proven R3 structure, 171 us).
// Block 64co x 128n (4h x 32w), 4 waves, wave tile 32co x 64n.
// LDS: Wl[9][64co][32ci], Xl[6hh][34wi][32ci].
// NEW: q/k blocks cover one full head's d=64, so qn/kn are computed in the
// epilogue (in-register reduce + cross-wave-pair combine via Snl) -- the
// separate norms kernel is gone.
// ---------------------------------------------------------------------------
__global__ __launch_bounds__(256) void conv3x3_mfma(
    const unsigned short* __restrict__ wqr,
    const unsigned short* __restrict__ xr,
    unsigned short* __restrict__ qt, unsigned short* __restrict__ kt,
    unsigned short* __restrict__ vt, float* __restrict__ qn,
    float* __restrict__ kn) {
  __shared__ __align__(16) unsigned short Wl[9 * 64 * 32];  // 36864 B
  __shared__ __align__(16) unsigned short Xl[6 * 34 * 32];  // 13056 B
  __shared__ float Snl[128];                                // norm partials

  const int tid = threadIdx.x;
  const int lane = tid & 63;
  const int wave = tid >> 6;
  const int wco = (wave & 1) * 32;
  const int wn = (wave >> 1) * 64;
  const int l15 = lane & 15;
  const int quad = lane >> 4;
  const int k8 = quad * 8;
  const int h0 = blockIdx.x * 4;
  const int co0 = blockIdx.y * 64;
  const int b = blockIdx.z;

  f32x4 acc[2][4];
  for (int ma = 0; ma < 2; ++ma)
    for (int nb = 0; nb < 4; ++nb) acc[ma][nb] = (f32x4){0.f, 0.f, 0.f, 0.f};

  for (int ci0 = 0; ci0 < 512; ci0 += 32) {
    __syncthreads();
    for (int idx = tid; idx < 2304; idx += 256) {
      int c4 = idx & 3;
      int co = (idx >> 2) & 63;
      int t = idx >> 8;
      *(u32x4*)(Wl + (t * 64 + co) * 32 + c4 * 8) =
          *(const u32x4*)(wqr + ((size_t)(t * 1536 + co0 + co) * 512 + ci0 + c4 * 8));
    }
    for (int idx = tid; idx < 816; idx += 256) {
      int c4 = idx & 3;
      int r = idx >> 2;
      int wi = r % 34;
      int hh = r / 34;
      int h = h0 - 1 + hh;
      int w = wi - 1;
      u32x4 v = {0u, 0u, 0u, 0u};
      if ((unsigned)h < 32u && (unsigned)w < 32u)
        v = *(const u32x4*)(xr + ((size_t)((b * 32 + h) * 32 + w) * 512 + ci0 + c4 * 8));
      *(u32x4*)(Xl + (hh * 34 + wi) * 32 + c4 * 8) = v;
    }
    __syncthreads();

#pragma unroll
    for (int t = 0; t < 9; ++t) {
      const int ky = t / 3, kx = t - ky * 3;
      bf16x8 af[2], bfr[4];
#pragma unroll
      for (int ma = 0; ma < 2; ++ma)
        af[ma] = *(const bf16x8*)(Wl + (t * 64 + wco + ma * 16 + l15) * 32 + k8);
#pragma unroll
      for (int nb = 0; nb < 4; ++nb) {
        int n = wn + nb * 16 + l15;
        int hh = (n >> 5) + ky;
        int wi = (n & 31) + kx;
        bfr[nb] = *(const bf16x8*)(Xl + (hh * 34 + wi) * 32 + k8);
      }
#pragma unroll
      for (int ma = 0; ma < 2; ++ma)
#pragma unroll
        for (int nb = 0; nb < 4; ++nb)
          acc[ma][nb] = __builtin_amdgcn_mfma_f32_16x16x32_bf16(
              af[ma], bfr[nb], acc[ma][nb], 0, 0, 0);
    }
  }

  // Epilogue: C/D layout col(n)=lane&15, row(m)=quad*4+reg.
  const int sec = co0 >> 9;
  const int g = (co0 & 511) >> 6;
  const int bg = b * 8 + g;
  if (sec < 2) {
    unsigned short* dst = (sec == 0) ? qt : kt;
#pragma unroll
    for (int ma = 0; ma < 2; ++ma)
#pragma unroll
      for (int nb = 0; nb < 4; ++nb) {
        int n = wn + nb * 16 + l15;
        int p = (h0 + (n >> 5)) * 32 + (n & 31);
        int db = wco + ma * 16 + quad * 4;
        u16x4 pk;
#pragma unroll
        for (int r = 0; r < 4; ++r) pk[r] = bf16rne(acc[ma][nb][r]);
        *(u16x4*)(dst + ((size_t)bg * 1024 + p) * 64 + db) = pk;
      }
    // Fused row norms: per n, sum acc^2 over this wave's 32 d, combine the
    // wave pair (wco 0 + wco 32) via Snl, then sqrt to qn/kn.
    float ps[4];
#pragma unroll
    for (int nb = 0; nb < 4; ++nb) {
      float s = 0.f;
#pragma unroll
      for (int ma = 0; ma < 2; ++ma)
#pragma unroll
        for (int r = 0; r < 4; ++r) s = fmaf(acc[ma][nb][r], acc[ma][nb][r], s);
      s += __shfl_down(s, 32);
      s += __shfl_down(s, 16);
      ps[nb] = s;  // valid in quad==0 lanes
    }
    if (wco == 0 && quad == 0)
#pragma unroll
      for (int nb = 0; nb < 4; ++nb) Snl[wn + nb * 16 + l15] = ps[nb];
    __syncthreads();
    if (wco == 32 && quad == 0) {
      float* ndst = (sec == 0) ? qn : kn;
#pragma unroll
      for (int nb = 0; nb < 4; ++nb) {
        int n = wn + nb * 16 + l15;
        int p = (h0 + (n >> 5)) * 32 + (n & 31);
        ndst[bg * 1024 + p] = sqrtf(Snl[n] + ps[nb] + SMOOTH);
      }
    }
  } else {
#pragma unroll
    for (int ma = 0; ma < 2; ++ma)
#pragma unroll
      for (int nb = 0; nb < 4; ++nb) {
        int n = wn + nb * 16 + l15;
        int p = (h0 + (n >> 5)) * 32 + (n & 31);
#pragma unroll
        for (int r = 0; r < 4; ++r) {
          int d = wco + ma * 16 + quad * 4 + r;
          vt[((size_t)bg * 64 + d) * 1024 + p] = bf16rne(acc[ma][nb][r]);
        }
      }
  }
}

// ---------------------------------------------------------------------------
// Kernel 3: attention, bf16 MFMA. Block = 64 i x (b,g); 4 waves, 16 i each.
// Grid 64x16 = 1024 blocks (4/CU) -- doubled vs R3 to cover latency.
// ---------------------------------------------------------------------------
__global__ __launch_bounds__(256) void attn_mfma(
    const unsigned short* __restrict__ qt, const unsigned short* __restrict__ kt,
    const unsigned short* __restrict__ vt, const float* __restrict__ qn,
    const float* __restrict__ kn, unsigned short* __restrict__ aob) {
  __shared__ __align__(16) unsigned short Kl[64 * 72];  // [j][d]
  __shared__ __align__(16) unsigned short Vl[64 * 72];  // [d][j]
  __shared__ __align__(16) unsigned short Sl[64 * 72];  // [i][j], 16 rows/wave

  const int tid = threadIdx.x;
  const int lane = tid & 63, wave = tid >> 6;
  const int l15 = lane & 15, quad = lane >> 4;
  const int bg = blockIdx.x;  // fastest -> same-bg blocks share XCD L2
  const int i0 = blockIdx.y * 64;
  const int iw = i0 + wave * 16;
  const int b = bg >> 3, g = bg & 7;

  bf16x8 qf[2];
#pragma unroll
  for (int ks = 0; ks < 2; ++ks)
    qf[ks] = *(const bf16x8*)(
        qt + ((size_t)bg * 1024 + iw + l15) * 64 + ks * 32 + quad * 8);

  float qn_i[4];
#pragma unroll
  for (int r = 0; r < 4; ++r) qn_i[r] = qn[bg * 1024 + iw + quad * 4 + r];

  f32x4 oacc[4];
  for (int nf = 0; nf < 4; ++nf) oacc[nf] = (f32x4){0.f, 0.f, 0.f, 0.f};

  unsigned short* Sw = Sl + wave * 16 * 72;

  for (int jt = 0; jt < 16; ++jt) {
    const int j0 = jt * 64;
    __syncthreads();
    for (int idx = tid; idx < 512; idx += 256) {
      int c8 = idx & 7, row = idx >> 3;
      *(u32x4*)(Kl + row * 72 + c8 * 8) =
          *(const u32x4*)(kt + ((size_t)bg * 1024 + j0 + row) * 64 + c8 * 8);
      *(u32x4*)(Vl + row * 72 + c8 * 8) =
          *(const u32x4*)(vt + ((size_t)bg * 64 + row) * 1024 + j0 + c8 * 8);
    }
    __syncthreads();

    f32x4 sacc[4];
    for (int nb = 0; nb < 4; ++nb) sacc[nb] = (f32x4){0.f, 0.f, 0.f, 0.f};
#pragma unroll
    for (int ks = 0; ks < 2; ++ks) {
#pragma unroll
      for (int nb = 0; nb < 4; ++nb) {
        bf16x8 kf = *(const bf16x8*)(Kl + (l15 + 16 * nb) * 72 + ks * 32 + quad * 8);
        sacc[nb] = __builtin_amdgcn_mfma_f32_16x16x32_bf16(
            qf[ks], kf, sacc[nb], 0, 0, 0);
      }
    }

#pragma unroll
    for (int nb = 0; nb < 4; ++nb) {
      float kn_j = kn[bg * 1024 + j0 + l15 + 16 * nb];
#pragma unroll
      for (int r = 0; r < 4; ++r) {
        float s = sacc[nb][r] * fastrcp(fmaf(qn_i[r], kn_j, SMOOTH));
        Sw[(quad * 4 + r) * 72 + l15 + 16 * nb] = bf16rne(s);
      }
    }
    // Sw is wave-private: lgkmcnt orders write->read, no barrier needed.
#pragma unroll
    for (int ks2 = 0; ks2 < 2; ++ks2) {
      bf16x8 sa = *(const bf16x8*)(Sw + l15 * 72 + ks2 * 32 + quad * 8);
#pragma unroll
      for (int nf = 0; nf < 4; ++nf) {
        bf16x8 vb = *(const bf16x8*)(Vl + (l15 + 16 * nf) * 72 + ks2 * 32 + quad * 8);
        oacc[nf] = __builtin_amdgcn_mfma_f32_16x16x32_bf16(sa, vb, oacc[nf], 0, 0, 0);
      }
    }
  }

#pragma unroll
  for (int nf = 0; nf < 4; ++nf)
#pragma unroll
    for (int r = 0; r < 4; ++r) {
      int i = iw + quad * 4 + r;
      int d = l15 + 16 * nf;
      aob[((size_t)(b * 1024) + i) * 512 + g * 64 + d] = bf16rne(oacc[nf][r]);
    }
}

// ---------------------------------------------------------------------------
// Kernel 4a: zero BN stat accumulators.
// ---------------------------------------------------------------------------
__global__ void zero_stats(float* __restrict__ sums, float* __restrict__ sumsq) {
  int t = blockIdx.x * 256 + threadIdx.x;
  if (t < 512) {
    sums[t] = 0.f;
    sumsq[t] = 0.f;
  }
}

// ---------------------------------------------------------------------------
// Kernel 4: 1x1 conv bf16 MFMA (M=512co, N=8192p, K=512ci) + BN stats.
// Block 64co x 64p (grid 1024 = 4/CU), 4 waves of 32co x 32p.
// ---------------------------------------------------------------------------
__global__ __launch_bounds__(256) void conv1x1_mfma(
    const unsigned short* __restrict__ wor, const unsigned short* __restrict__ aob,
    float* __restrict__ y, float* __restrict__ sums, float* __restrict__ sumsq) {
  __shared__ __align__(16) unsigned short Wl[64 * 40];  // [co][ci]
  __shared__ __align__(16) unsigned short Bl[64 * 40];  // [p][ci]

  const int tid = threadIdx.x;
  const int lane = tid & 63, wave = tid >> 6;
  const int l15 = lane & 15, quad = lane >> 4;
  const int wco = (wave & 1) * 32;
  const int wp = (wave >> 1) * 32;
  const int p0 = blockIdx.x * 64;
  const int co0 = blockIdx.y * 64;
  const int b = blockIdx.z;

  f32x4 acc[2][2];
  for (int ma = 0; ma < 2; ++ma)
    for (int nb = 0; nb < 2; ++nb) acc[ma][nb] = (f32x4){0.f, 0.f, 0.f, 0.f};

  for (int ci0 = 0; ci0 < 512; ci0 += 32) {
    __syncthreads();
    {
      int c4 = tid & 3, co = tid >> 2;
      *(u32x4*)(Wl + co * 40 + c4 * 8) =
          *(const u32x4*)(wor + (size_t)(co0 + co) * 512 + ci0 + c4 * 8);
      *(u32x4*)(Bl + co * 40 + c4 * 8) =
          *(const u32x4*)(aob + ((size_t)(b * 1024) + p0 + co) * 512 + ci0 + c4 * 8);
    }
    __syncthreads();

    bf16x8 af[2], bf[2];
#pragma unroll
    for (int ma = 0; ma < 2; ++ma)
      af[ma] = *(const bf16x8*)(Wl + (wco + ma * 16 + l15) * 40 + quad * 8);
#pragma unroll
    for (int nb = 0; nb < 2; ++nb)
      bf[nb] = *(const bf16x8*)(Bl + (wp + nb * 16 + l15) * 40 + quad * 8);
#pragma unroll
    for (int ma = 0; ma < 2; ++ma)
#pragma unroll
      for (int nb = 0; nb < 2; ++nb)
        acc[ma][nb] = __builtin_amdgcn_mfma_f32_16x16x32_bf16(
            af[ma], bf[nb], acc[ma][nb], 0, 0, 0);
  }

#pragma unroll
  for (int ma = 0; ma < 2; ++ma)
#pragma unroll
    for (int r = 0; r < 4; ++r) {
      int co = co0 + wco + ma * 16 + quad * 4 + r;
      float s1 = 0.f, s2 = 0.f;
#pragma unroll
      for (int nb = 0; nb < 2; ++nb) {
        float v = acc[ma][nb][r];
        y[((size_t)(b * 512) + co) * 1024 + p0 + wp + nb * 16 + l15] = v;
        s1 += v;
        s2 = fmaf(v, v, s2);
      }
      for (int off = 8; off >= 1; off >>= 1) {
        s1 += __shfl_down(s1, off, 16);
        s2 += __shfl_down(s2, off, 16);
      }
      if (l15 == 0) {
        atomicAdd(&sums[co], s1);
        atomicAdd(&sumsq[co], s2);
      }
    }
}

// ---------------------------------------------------------------------------
// Kernel 5: BatchNorm (batch stats, biased var) + ReLU, float4.
// ---------------------------------------------------------------------------
__global__ void bn_kernel(const float* __restrict__ y,
                          const float* __restrict__ sums,
                          const float* __restrict__ sumsq,
                          const float* __restrict__ gamma,
                          const float* __restrict__ beta,
                          float* __restrict__ out) {
  int idx = blockIdx.x * 256 + threadIdx.x;  // 1048576 float4s
  int c = (idx >> 8) & 511;
  float4 v = ((const float4*)y)[idx];
  float mean = sums[c] * (1.f / 8192.f);
  float var = sumsq[c] * (1.f / 8192.f) - mean * mean;
  float sc = gamma[c] * rsqrtf(var + BN_EPS);
  float sh = beta[c] - mean * sc;
  float4 r;
  r.x = fmaxf(0.f, fmaf(v.x, sc, sh));
  r.y = fmaxf(0.f, fmaf(v.y, sc, sh));
  r.z = fmaxf(0.f, fmaf(v.z, sc, sh));
  r.w = fmaxf(0.f, fmaf(v.w, sc, sh));
  ((float4*)out)[idx] = r;
}

// ---------------------------------------------------------------------------
extern "C" void kernel_launch(void* const* d_in, const int* in_sizes, int n_in,
                              void* d_out, int out_size, void* d_ws,
                              size_t ws_size, hipStream_t stream) {
  const float* x = (const float*)d_in[0];
  const float* wq = (const float*)d_in[1];
  const float* wo = (const float*)d_in[2];
  const float* gamma = (const float*)d_in[3];
  const float* beta = (const float*)d_in[4];
  float* out = (float*)d_out;

  // Workspace layout (~74 MB, all 16B aligned)
  unsigned short* qt = (unsigned short*)d_ws;          // [64][1024][64]
  unsigned short* kt = qt + (size_t)4194304;
  unsigned short* vt = kt + (size_t)4194304;           // [64][64][1024]
  unsigned short* aob = vt + (size_t)4194304;          // [8][1024][512]
  unsigned short* wqr = aob + (size_t)4194304;         // [9][1536][512]
  unsigned short* wor = wqr + (size_t)7077888;         // [512][512]
  unsigned short* xr = wor + (size_t)262144;           // [8][1024][512]
  float* qn = (float*)(xr + (size_t)4194304);          // [64][1024]
  float* kn = qn + 65536;
  float* y = kn + 65536;                               // [8][512][1024] fp32
  float* sums = y + (size_t)4194304;
  float* sumsq = sums + 512;

  repack_w<<<dim3(3072), 256, 0, stream>>>(wq, wqr);
  repack_x<<<dim3(512), 256, 0, stream>>>(x, xr);
  repack_wo<<<dim3(1024), 256, 0, stream>>>(wo, wor);
  zero_stats<<<dim3(2), 256, 0, stream>>>(sums, sumsq);
  conv3x3_mfma<<<dim3(8, 24, 8), 256, 0, stream>>>(wqr, xr, qt, kt, vt, qn, kn);
  attn_mfma<<<dim3(64, 16), 256, 0, stream>>>(qt, kt, vt, qn, kn, aob);
  conv1x1_mfma<<<dim3(16, 8, 8), 256, 0, stream>>>(wor, aob, y, sums, sumsq);
  bn_kernel<<<dim3(4096), 256, 0, stream>>>(y, sums, sumsq, gamma, beta, out);
}